// Round 1
// baseline (401.201 us; speedup 1.0000x reference)
//
#include <hip/hip_runtime.h>
#include <math.h>

// Problem constants
constexpr int C    = 128;
constexpr int K    = 16;
constexpr int H    = 128;
constexpr int NB2  = 256;   // blocks for point-stat partial reduction
constexpr int WPTS = 32;    // points per wave
constexpr int PB   = 128;   // points per block (4 waves)
constexpr int HSU  = 68;    // activation row stride in u32 (136 bf16)

// Packed-weight offsets (bf16 elems) in ws: fragment order
constexpr int WT_MIX   = 0;        // K=384 -> 12 chunks
constexpr int WT_GATE  = 49152;    // K=256 -> 8 chunks
constexpr int WT_CP2   = 81920;    // K=128 -> 4 chunks
constexpr int WT_MIX2  = 98304;
constexpr int WT_GATE2 = 114688;
constexpr int WT_OUT   = 131072;
constexpr int WT_TOTAL = 147456;

typedef __attribute__((ext_vector_type(8))) short short8;
typedef __attribute__((ext_vector_type(4))) short short4v;
typedef __attribute__((ext_vector_type(4))) float f32x4;
typedef _Float16 h2 __attribute__((ext_vector_type(2)));

__device__ __forceinline__ short f2bf(float f) {
    unsigned u = __float_as_uint(f);
    unsigned r = (u + 0x7fffu + ((u >> 16) & 1u)) >> 16;
    return (short)r;
}
__device__ __forceinline__ float bflo(unsigned v) { return __uint_as_float(v << 16); }
__device__ __forceinline__ float bfhi(unsigned v) { return __uint_as_float(v & 0xffff0000u); }
__device__ __forceinline__ float bf2f(short s) {
    return __uint_as_float(((unsigned)(unsigned short)s) << 16);
}
__device__ __forceinline__ float rcpf(float v) { return __builtin_amdgcn_rcpf(v); }

// e5m2 = truncated fp16
__device__ __forceinline__ unsigned f2e5m2(float x) {
    union { _Float16 h; unsigned short u; } cv;
    cv.h = (_Float16)x;
    return ((unsigned)cv.u + 0x7Fu + ((cv.u >> 8) & 1u)) >> 8;
}

// A&S 7.1.26 erf-based exact-GELU (|erf err| < 1.5e-7)
__device__ __forceinline__ float gelu_f(float x) {
    float a = fabsf(x) * 0.70710678118654752440f;
    float t = rcpf(1.0f + 0.3275911f * a);
    float p = t * (0.254829592f + t * (-0.284496736f + t * (1.421413741f
            + t * (-1.453152027f + t * 1.061405429f))));
    float e = __expf(-a * a);
    float er = 1.0f - p * e;
    return 0.5f * x * (1.0f + copysignf(er, x));
}
__device__ __forceinline__ float sigm(float v) { return rcpf(1.0f + __expf(-v)); }

// ---------------------------------------------------------------------------
// Merged prep: weight pack | zero rows | pts4 | pstat partial | layernorm
// (all mutually independent; one launch instead of three)
// ---------------------------------------------------------------------------
__global__ __launch_bounds__(256) void prep_all(
    const float* __restrict__ mix_w1, const float* __restrict__ gate_w1,
    const float* __restrict__ cp_w2,  const float* __restrict__ mix_w2,
    const float* __restrict__ gate_w2, const float* __restrict__ out_w,
    const float* __restrict__ points, const float* __restrict__ feats,
    const float* __restrict__ ln_g, const float* __restrict__ ln_b,
    short* __restrict__ wt, unsigned* __restrict__ xb,
    unsigned short* __restrict__ xg, float* __restrict__ pts4,
    float* __restrict__ partial, int n, int np4)
{
    __shared__ float sm[256];
    const int b   = blockIdx.x;
    const int tid = threadIdx.x;

    if (b < 36) {
        // weight pack into MFMA fragment order
        const float* src; int off; int c; bool skip256 = false;
        if (b < 12)      { src = mix_w1;  off = WT_MIX;   c = b;      skip256 = true; }
        else if (b < 20) { src = gate_w1; off = WT_GATE;  c = b - 12; }
        else if (b < 24) { src = cp_w2;   off = WT_CP2;   c = b - 20; }
        else if (b < 28) { src = mix_w2;  off = WT_MIX2;  c = b - 24; }
        else if (b < 32) { src = gate_w2; off = WT_GATE2; c = b - 28; }
        else             { src = out_w;   off = WT_OUT;   c = b - 32; }
        for (int ii = 0; ii < 16; ++ii) {
            int e = ii * 256 + tid;
            int j = e & 7, l = (e >> 3) & 63, t = e >> 9;
            int k = c * 32 + ((l >> 4) * 8) + j;
            int nn = t * 16 + (l & 15);
            int kk = (skip256 && k >= 256) ? k + 1 : k;
            wt[off + c * 4096 + e] = f2bf(src[kk * C + nn]);
        }
        return;
    }
    if (b == 36) {
        if (tid < 64) xb[(size_t)n * 64 + tid] = 0u;
        else if (tid < 96) ((unsigned*)xg)[(size_t)n * 32 + (tid - 64)] = 0u;
        return;
    }
    if (b < 37 + np4) {
        int i = (b - 37) * 256 + tid;
        if (i < n) {
            pts4[i * 4 + 0] = points[i * 3 + 0];
            pts4[i * 4 + 1] = points[i * 3 + 1];
            pts4[i * 4 + 2] = points[i * 3 + 2];
            pts4[i * 4 + 3] = 0.0f;
        } else if (i == n) {
            pts4[i * 4 + 0] = 0.0f; pts4[i * 4 + 1] = 0.0f;
            pts4[i * 4 + 2] = 0.0f; pts4[i * 4 + 3] = 0.0f;
        }
        return;
    }
    if (b < 37 + np4 + NB2) {
        // pstat partial
        const int bb = b - 37 - np4;
        float s[3] = {0, 0, 0};
        float mn[3] = {1e30f, 1e30f, 1e30f};
        float mx[3] = {-1e30f, -1e30f, -1e30f};
        for (int i = bb * 256 + tid; i < n; i += NB2 * 256) {
            #pragma unroll
            for (int c = 0; c < 3; ++c) {
                float v = points[i * 3 + c];
                s[c] += v; mn[c] = fminf(mn[c], v); mx[c] = fmaxf(mx[c], v);
            }
        }
        for (int q = 0; q < 9; ++q) {
            float v = (q < 3) ? s[q] : (q < 6) ? mn[q - 3] : mx[q - 6];
            sm[tid] = v;
            __syncthreads();
            for (int o = 128; o > 0; o >>= 1) {
                if (tid < o) {
                    float a = sm[tid], c = sm[tid + o];
                    sm[tid] = (q < 3) ? a + c : (q < 6) ? fminf(a, c) : fmaxf(a, c);
                }
                __syncthreads();
            }
            if (tid == 0) partial[bb * 9 + q] = sm[0];
            __syncthreads();
        }
        return;
    }

    // layernorm role: one wave per point
    const int lane = tid & 63;
    const int wave = tid >> 6;
    const int i = (b - 37 - np4 - NB2) * 4 + wave;
    if (i >= n) return;
    const float2 f = *(const float2*)(feats + i * C + 2 * lane);
    float s = f.x + f.y;
    #pragma unroll
    for (int o = 32; o > 0; o >>= 1) s += __shfl_xor(s, o, 64);
    const float mu = s * (1.0f / C);
    const float d0 = f.x - mu, d1 = f.y - mu;
    float v = d0 * d0 + d1 * d1;
    #pragma unroll
    for (int o = 32; o > 0; o >>= 1) v += __shfl_xor(v, o, 64);
    const float rs = rsqrtf(v * (1.0f / C) + 1e-5f);
    const float x0 = d0 * rs * ln_g[2 * lane] + ln_b[2 * lane];
    const float x1 = d1 * rs * ln_g[2 * lane + 1] + ln_b[2 * lane + 1];
    xb[(size_t)i * 64 + lane] =
        (unsigned)(unsigned short)f2bf(x0) | ((unsigned)(unsigned short)f2bf(x1) << 16);
    xg[(size_t)i * 64 + lane] =
        (unsigned short)(f2e5m2(x0) | (f2e5m2(x1) << 8));
}

__global__ __launch_bounds__(256) void pstat_final(
    const float* __restrict__ partial, float* __restrict__ stats, int n)
{
    __shared__ float sm[256];
    const int tid = threadIdx.x;
    for (int q = 0; q < 9; ++q) {
        float v = partial[tid * 9 + q];
        sm[tid] = v;
        __syncthreads();
        for (int o = 128; o > 0; o >>= 1) {
            if (tid < o) {
                float a = sm[tid], c = sm[tid + o];
                sm[tid] = (q < 3) ? a + c : (q < 6) ? fminf(a, c) : fmaxf(a, c);
            }
            __syncthreads();
        }
        if (tid == 0) sm[q] = sm[0];
        __syncthreads();
    }
    if (tid < 3) {
        float mean = sm[tid] / (float)n;
        float scale = fmaxf(fmaxf(sm[6 + tid] - mean, mean - sm[3 + tid]), 1e-6f);
        stats[tid] = mean;
        stats[3 + tid] = scale;
    }
}

// ---------------------------------------------------------------------------
// Gather kernel (phases A+B): tiny LDS -> high occupancy to hide L2/L3
// gather latency. Writes mean_feat rows (bf16) + boundary score to workspace.
// ---------------------------------------------------------------------------
__global__ __launch_bounds__(256, 4) void gather_kernel(
    const unsigned* __restrict__ xb, const unsigned* __restrict__ xg,
    const float* __restrict__ pts4, const int* __restrict__ neighbors,
    const float* __restrict__ bd_w1, const float* __restrict__ bd_b1,
    const float* __restrict__ bd_w2, const float* __restrict__ bd_b2,
    unsigned* __restrict__ mf_g, float* __restrict__ bd_g, int n)
{
    __shared__ int   nb_s[4][512];
    __shared__ float denom_s[128];
    __shared__ float cd_s[128];

    const int tid  = threadIdx.x;
    const int lane = tid & 63;
    const int w    = tid >> 6;
    const int i0   = blockIdx.x * PB;
    const int wv32 = w * WPTS;
    const int i0w  = i0 + wv32;
    int* nb_w = nb_s[w];

    // ================= Phase A: neighbor metadata =================
    {
        const int p0 = lane >> 2;               // 0..15
        const int jb = 4 * (lane & 3);
        const int r0 = min(i0w + p0, n - 1);
        const int r1 = min(i0w + 16 + p0, n - 1);
        const int4 A0 = *(const int4*)(neighbors + (size_t)r0 * K + jb);
        const int4 A1 = *(const int4*)(neighbors + (size_t)r1 * K + jb);

        const int q00 = ((unsigned)A0.x < (unsigned)n) ? A0.x : n;
        const int q01 = ((unsigned)A0.y < (unsigned)n) ? A0.y : n;
        const int q02 = ((unsigned)A0.z < (unsigned)n) ? A0.z : n;
        const int q03 = ((unsigned)A0.w < (unsigned)n) ? A0.w : n;
        const int q10 = ((unsigned)A1.x < (unsigned)n) ? A1.x : n;
        const int q11 = ((unsigned)A1.y < (unsigned)n) ? A1.y : n;
        const int q12 = ((unsigned)A1.z < (unsigned)n) ? A1.z : n;
        const int q13 = ((unsigned)A1.w < (unsigned)n) ? A1.w : n;

        *(int4*)&nb_w[4 * lane]       = make_int4(q00, q01, q02, q03);
        *(int4*)&nb_w[256 + 4 * lane] = make_int4(q10, q11, q12, q13);

        float c0 = (float)((q00 != n) + (q01 != n) + (q02 != n) + (q03 != n));
        float c1 = (float)((q10 != n) + (q11 != n) + (q12 != n) + (q13 != n));
        c0 += __shfl_xor(c0, 1, 64); c0 += __shfl_xor(c0, 2, 64);
        c1 += __shfl_xor(c1, 1, 64); c1 += __shfl_xor(c1, 2, 64);
        const float d0 = fmaxf(c0, 1.0f), d1 = fmaxf(c1, 1.0f);
        if ((lane & 3) == 0) {
            denom_s[wv32 + p0]      = d0;
            denom_s[wv32 + 16 + p0] = d1;
        }

        f32x4 s0 = *(const f32x4*)(pts4 + 4 * q00);
        s0 += *(const f32x4*)(pts4 + 4 * q01);
        s0 += *(const f32x4*)(pts4 + 4 * q02);
        s0 += *(const f32x4*)(pts4 + 4 * q03);
        f32x4 s1 = *(const f32x4*)(pts4 + 4 * q10);
        s1 += *(const f32x4*)(pts4 + 4 * q11);
        s1 += *(const f32x4*)(pts4 + 4 * q12);
        s1 += *(const f32x4*)(pts4 + 4 * q13);
        #pragma unroll
        for (int c = 0; c < 3; ++c) {
            s0[c] += __shfl_xor(s0[c], 1, 64); s0[c] += __shfl_xor(s0[c], 2, 64);
            s1[c] += __shfl_xor(s1[c], 1, 64); s1[c] += __shfl_xor(s1[c], 2, 64);
        }
        if ((lane & 3) == 0) {
            const float rd0 = rcpf(d0), rd1 = rcpf(d1);
            const f32x4 pv0 = *(const f32x4*)(pts4 + 4 * r0);
            const f32x4 pv1 = *(const f32x4*)(pts4 + 4 * r1);
            const float e00 = pv0[0] - s0[0] * rd0, e01 = pv0[1] - s0[1] * rd0, e02 = pv0[2] - s0[2] * rd0;
            const float e10 = pv1[0] - s1[0] * rd1, e11 = pv1[1] - s1[1] * rd1, e12 = pv1[2] - s1[2] * rd1;
            cd_s[wv32 + p0]      = sqrtf(e00 * e00 + e01 * e01 + e02 * e02);
            cd_s[wv32 + 16 + p0] = sqrtf(e10 * e10 + e11 * e11 + e12 * e12);
        }
    }

    // ============ Phase B: pipelined fp8 gather, 2 points per iteration ======
    {
        const int ul   = lane & 31;
        const int half = lane >> 5;
        float w1f[4], w1c[4], b1v[4], w2v[4];
        #pragma unroll
        for (int j = 0; j < 4; ++j) {
            int u = ul + 32 * j;
            w1f[j] = bd_w1[u]; w1c[j] = bd_w1[H + u];
            b1v[j] = bd_b1[u]; w2v[j] = bd_w2[u];
        }
        const float bb2 = bd_b2[0];

        unsigned cur[16], nxt[16];
        #pragma unroll
        for (int k = 0; k < K; ++k) {
            const int r = nb_w[half * K + k];
            cur[k] = xg[(size_t)r * 32 + ul];
        }
        for (int pr = 0; pr < 16; ++pr) {
            if (pr < 15) {
                #pragma unroll
                for (int k = 0; k < K; ++k) {
                    const int r = nb_w[((pr + 1) * 2 + half) * K + k];
                    nxt[k] = xg[(size_t)r * 32 + ul];
                }
            }
            // packed-f16 e5m2 accumulate: [b0,b2] and [b1,b3] per u32
            union UH { unsigned u; h2 h; };
            UH a02, a13; a02.u = 0u; a13.u = 0u;
            #pragma unroll
            for (int k = 0; k < K; ++k) {
                const unsigned u = cur[k];
                UH lo, hi;
                lo.u = (u << 8) & 0xFF00FF00u;
                hi.u = u & 0xFF00FF00u;
                a02.h += lo.h;
                a13.h += hi.h;
            }
            float f0 = (float)a02.h[0], f2 = (float)a02.h[1];
            float f1 = (float)a13.h[0], f3 = (float)a13.h[1];

            const int p = 2 * pr + half;
            const float rden = rcpf(denom_s[wv32 + p]);
            f0 *= rden; f1 *= rden; f2 *= rden; f3 *= rden;
            short4v pk; pk[0] = f2bf(f0); pk[1] = f2bf(f1); pk[2] = f2bf(f2); pk[3] = f2bf(f3);
            if (i0w + p < n)
                *(short4v*)((short*)mf_g + (size_t)(i0w + p) * 128 + ul * 4) = pk;

            const int ipp = min(i0w + p, n - 1);
            const uint2 xv = *(const uint2*)(xb + (size_t)ipp * 64 + 2 * ul);
            const float d0 = bflo(xv.x) - f0, d1 = bfhi(xv.x) - f1;
            const float d2 = bflo(xv.y) - f2, d3 = bfhi(xv.y) - f3;
            float ss = d0 * d0 + d1 * d1 + d2 * d2 + d3 * d3;
            #pragma unroll
            for (int o = 16; o > 0; o >>= 1) ss += __shfl_xor(ss, o, 64);
            const float fd = sqrtf(ss);
            const float cd = cd_s[wv32 + p];
            float s = 0.0f;
            #pragma unroll
            for (int j = 0; j < 4; ++j)
                s += gelu_f(fd * w1f[j] + cd * w1c[j] + b1v[j]) * w2v[j];
            #pragma unroll
            for (int o = 16; o > 0; o >>= 1) s += __shfl_xor(s, o, 64);
            if (ul == 0 && i0w + p < n) bd_g[i0w + p] = sigm(s + bb2);
            #pragma unroll
            for (int k = 0; k < K; ++k) cur[k] = nxt[k];
        }
    }
}

// ---------------------------------------------------------------------------
// GEMM kernel: hid LDS only (34.8 KB) -> 3-4 blocks/CU. Gate-first ordering
// keeps only a bf16-packed gate vector (32 VGPR) live across the mix GEMMs.
// x and mf fragments stream straight from global (L2/L3-resident).
// ---------------------------------------------------------------------------
__global__ __launch_bounds__(256, 3) void gemm_kernel(
    const unsigned* __restrict__ xb, const unsigned* __restrict__ mf_g,
    const float* __restrict__ bd_g, const float* __restrict__ pts4,
    const float* __restrict__ feats, const float* __restrict__ stats,
    const short* __restrict__ wt,
    const float* __restrict__ cp_w1, const float* __restrict__ cp_b1,
    const float* __restrict__ cp_b2,
    const float* __restrict__ mix_w1, const float* __restrict__ mix_b1,
    const float* __restrict__ mix_b2,
    const float* __restrict__ gate_w1, const float* __restrict__ gate_b1,
    const float* __restrict__ gate_b2,
    const float* __restrict__ out_b, float* __restrict__ out, int n)
{
    __shared__ __align__(16) unsigned hid_s[128 * HSU];   // 34816 B

    const int tid  = threadIdx.x;
    const int lane = tid & 63;
    const int w    = tid >> 6;
    const int m16  = lane & 15;
    const int h4   = lane >> 4;
    const int i0   = blockIdx.x * PB;
    const int wv32 = w * WPTS;

    const int pr0 = wv32 + m16, pr1 = wv32 + 16 + m16;
    const int ig0 = i0 + pr0,   ig1 = i0 + pr1;
    const int ip0 = min(ig0, n - 1), ip1 = min(ig1, n - 1);
    const unsigned* xr0  = xb + (size_t)ip0 * 64;
    const unsigned* xr1  = xb + (size_t)ip1 * 64;
    const unsigned* mfr0 = mf_g + (size_t)ip0 * 64;
    const unsigned* mfr1 = mf_g + (size_t)ip1 * 64;
    unsigned* hr0 = hid_s + pr0 * HSU;
    unsigned* hr1 = hid_s + pr1 * HSU;

    const float bdp0 = bd_g[ip0], bdp1 = bd_g[ip1];

    // ---- gate1 (K=256: x | mf) + rank-1 + bias, GELU -> hid ----
    {
        f32x4 a0[8], a1[8];
        #pragma unroll
        for (int t = 0; t < 8; ++t) { a0[t] = (f32x4)0.0f; a1[t] = (f32x4)0.0f; }
        #pragma unroll
        for (int c = 0; c < 8; ++c) {
            short8 af0, af1;
            if (c < 4) {
                af0 = *(const short8*)(xr0 + c * 16 + h4 * 4);
                af1 = *(const short8*)(xr1 + c * 16 + h4 * 4);
            } else {
                af0 = *(const short8*)(mfr0 + (c - 4) * 16 + h4 * 4);
                af1 = *(const short8*)(mfr1 + (c - 4) * 16 + h4 * 4);
            }
            const short* wgc = wt + WT_GATE + c * 4096 + lane * 8;
            #pragma unroll
            for (int t = 0; t < 8; ++t) {
                const short8 wf = *(const short8*)(wgc + t * 512);
                a0[t] = __builtin_amdgcn_mfma_f32_16x16x32_bf16(wf, af0, a0[t], 0, 0, 0);
                a1[t] = __builtin_amdgcn_mfma_f32_16x16x32_bf16(wf, af1, a1[t], 0, 0, 0);
            }
        }
        #pragma unroll
        for (int t = 0; t < 8; ++t) {
            const int col = t * 16 + h4 * 4;
            const f32x4 wb = *(const f32x4*)(gate_w1 + 256 * C + col);
            const f32x4 bb = *(const f32x4*)(gate_b1 + col);
            const f32x4 v0 = a0[t] + bdp0 * wb + bb;
            const f32x4 v1 = a1[t] + bdp1 * wb + bb;
            short4v pk0, pk1;
            #pragma unroll
            for (int r = 0; r < 4; ++r) { pk0[r] = f2bf(gelu_f(v0[r])); pk1[r] = f2bf(gelu_f(v1[r])); }
            *(short4v*)((short*)hr0 + col) = pk0;
            *(short4v*)((short*)hr1 + col) = pk1;
        }
    }

    // ---- gate2 -> sigmoid packed to bf16 regs (32 VGPR live downstream) ----
    short4v gpk0[8], gpk1[8];
    {
        f32x4 a0[8], a1[8];
        #pragma unroll
        for (int t = 0; t < 8; ++t) { a0[t] = (f32x4)0.0f; a1[t] = (f32x4)0.0f; }
        #pragma unroll
        for (int c = 0; c < 4; ++c) {
            const short8 af0 = *(const short8*)(hr0 + c * 16 + h4 * 4);
            const short8 af1 = *(const short8*)(hr1 + c * 16 + h4 * 4);
            const short* wgc = wt + WT_GATE2 + c * 4096 + lane * 8;
            #pragma unroll
            for (int t = 0; t < 8; ++t) {
                const short8 wf = *(const short8*)(wgc + t * 512);
                a0[t] = __builtin_amdgcn_mfma_f32_16x16x32_bf16(wf, af0, a0[t], 0, 0, 0);
                a1[t] = __builtin_amdgcn_mfma_f32_16x16x32_bf16(wf, af1, a1[t], 0, 0, 0);
            }
        }
        #pragma unroll
        for (int t = 0; t < 8; ++t) {
            const f32x4 bb = *(const f32x4*)(gate_b2 + t * 16 + h4 * 4);
            #pragma unroll
            for (int r = 0; r < 4; ++r) {
                gpk0[t][r] = f2bf(sigm(a0[t][r] + bb[r]));
                gpk1[t][r] = f2bf(sigm(a1[t][r] + bb[r]));
            }
        }
    }

    // ---- cp MLP: hidden from regs, cp2 GEMM -> ce into hid ----
    {
        const f32x4 pv0 = *(const f32x4*)(pts4 + 4 * ip0);
        const f32x4 pv1 = *(const f32x4*)(pts4 + 4 * ip1);
        const float px0 = (pv0[0] - stats[0]) * rcpf(stats[3]);
        const float py0 = (pv0[1] - stats[1]) * rcpf(stats[4]);
        const float pz0 = (pv0[2] - stats[2]) * rcpf(stats[5]);
        const float px1 = (pv1[0] - stats[0]) * rcpf(stats[3]);
        const float py1 = (pv1[1] - stats[1]) * rcpf(stats[4]);
        const float pz1 = (pv1[2] - stats[2]) * rcpf(stats[5]);
        f32x4 a0[8], a1[8];
        #pragma unroll
        for (int t = 0; t < 8; ++t) { a0[t] = (f32x4)0.0f; a1[t] = (f32x4)0.0f; }
        #pragma unroll
        for (int c = 0; c < 4; ++c) {
            short8 af0, af1;
            #pragma unroll
            for (int j = 0; j < 8; ++j) {
                const int hh = c * 32 + h4 * 8 + j;
                const float wa = cp_w1[hh], wb = cp_w1[H + hh], wc2 = cp_w1[2 * H + hh];
                const float bb = cp_b1[hh];
                af0[j] = f2bf(gelu_f(bb + px0 * wa + py0 * wb + pz0 * wc2));
                af1[j] = f2bf(gelu_f(bb + px1 * wa + py1 * wb + pz1 * wc2));
            }
            const short* wcp = wt + WT_CP2 + c * 4096 + lane * 8;
            #pragma unroll
            for (int t = 0; t < 8; ++t) {
                const short8 wf = *(const short8*)(wcp + t * 512);
                a0[t] = __builtin_amdgcn_mfma_f32_16x16x32_bf16(wf, af0, a0[t], 0, 0, 0);
                a1[t] = __builtin_amdgcn_mfma_f32_16x16x32_bf16(wf, af1, a1[t], 0, 0, 0);
            }
        }
        #pragma unroll
        for (int t = 0; t < 8; ++t) {
            const f32x4 bb = *(const f32x4*)(cp_b2 + t * 16 + h4 * 4);
            const f32x4 v0 = a0[t] + bb, v1 = a1[t] + bb;
            short4v pk0, pk1;
            #pragma unroll
            for (int r = 0; r < 4; ++r) { pk0[r] = f2bf(v0[r]); pk1[r] = f2bf(v1[r]); }
            *(short4v*)((short*)hr0 + t * 16 + h4 * 4) = pk0;
            *(short4v*)((short*)hr1 + t * 16 + h4 * 4) = pk1;
        }
    }

    // ---- mix1 (K=384: x | mf | ce) + rank-1 + bias, GELU -> hid ----
    {
        f32x4 a0[8], a1[8];
        #pragma unroll
        for (int t = 0; t < 8; ++t) { a0[t] = (f32x4)0.0f; a1[t] = (f32x4)0.0f; }
        #pragma unroll
        for (int c = 0; c < 12; ++c) {
            short8 af0, af1;
            if (c < 4) {
                af0 = *(const short8*)(xr0 + c * 16 + h4 * 4);
                af1 = *(const short8*)(xr1 + c * 16 + h4 * 4);
            } else if (c < 8) {
                af0 = *(const short8*)(mfr0 + (c - 4) * 16 + h4 * 4);
                af1 = *(const short8*)(mfr1 + (c - 4) * 16 + h4 * 4);
            } else {
                af0 = *(const short8*)(hr0 + (c - 8) * 16 + h4 * 4);
                af1 = *(const short8*)(hr1 + (c - 8) * 16 + h4 * 4);
            }
            const short* wmc = wt + WT_MIX + c * 4096 + lane * 8;
            #pragma unroll
            for (int t = 0; t < 8; ++t) {
                const short8 wf = *(const short8*)(wmc + t * 512);
                a0[t] = __builtin_amdgcn_mfma_f32_16x16x32_bf16(wf, af0, a0[t], 0, 0, 0);
                a1[t] = __builtin_amdgcn_mfma_f32_16x16x32_bf16(wf, af1, a1[t], 0, 0, 0);
            }
        }
        #pragma unroll
        for (int t = 0; t < 8; ++t) {
            const int col = t * 16 + h4 * 4;
            const f32x4 wb = *(const f32x4*)(mix_w1 + 256 * C + col);
            const f32x4 bb = *(const f32x4*)(mix_b1 + col);
            const f32x4 v0 = a0[t] + bdp0 * wb + bb;
            const f32x4 v1 = a1[t] + bdp1 * wb + bb;
            short4v pk0, pk1;
            #pragma unroll
            for (int r = 0; r < 4; ++r) { pk0[r] = f2bf(gelu_f(v0[r])); pk1[r] = f2bf(gelu_f(v1[r])); }
            *(short4v*)((short*)hr0 + col) = pk0;
            *(short4v*)((short*)hr1 + col) = pk1;
        }
    }

    // ---- mix2 -> refined; gate-multiply -> hid (overwrite) ----
    {
        f32x4 a0[8], a1[8];
        #pragma unroll
        for (int t = 0; t < 8; ++t) { a0[t] = (f32x4)0.0f; a1[t] = (f32x4)0.0f; }
        #pragma unroll
        for (int c = 0; c < 4; ++c) {
            const short8 af0 = *(const short8*)(hr0 + c * 16 + h4 * 4);
            const short8 af1 = *(const short8*)(hr1 + c * 16 + h4 * 4);
            const short* wmc = wt + WT_MIX2 + c * 4096 + lane * 8;
            #pragma unroll
            for (int t = 0; t < 8; ++t) {
                const short8 wf = *(const short8*)(wmc + t * 512);
                a0[t] = __builtin_amdgcn_mfma_f32_16x16x32_bf16(wf, af0, a0[t], 0, 0, 0);
                a1[t] = __builtin_amdgcn_mfma_f32_16x16x32_bf16(wf, af1, a1[t], 0, 0, 0);
            }
        }
        #pragma unroll
        for (int t = 0; t < 8; ++t) {
            const int col = t * 16 + h4 * 4;
            const f32x4 bb = *(const f32x4*)(mix_b2 + col);
            const f32x4 v0 = a0[t] + bb, v1 = a1[t] + bb;
            short4v pk0, pk1;
            #pragma unroll
            for (int r = 0; r < 4; ++r) {
                pk0[r] = f2bf(bf2f(gpk0[t][r]) * v0[r]);
                pk1[r] = f2bf(bf2f(gpk1[t][r]) * v1[r]);
            }
            *(short4v*)((short*)hr0 + col) = pk0;
            *(short4v*)((short*)hr1 + col) = pk1;
        }
    }

    // ---- out GEMM + bias + residual -> global store ----
    {
        f32x4 a0[8], a1[8];
        #pragma unroll
        for (int t = 0; t < 8; ++t) { a0[t] = (f32x4)0.0f; a1[t] = (f32x4)0.0f; }
        #pragma unroll
        for (int c = 0; c < 4; ++c) {
            const short8 af0 = *(const short8*)(hr0 + c * 16 + h4 * 4);
            const short8 af1 = *(const short8*)(hr1 + c * 16 + h4 * 4);
            const short* woc = wt + WT_OUT + c * 4096 + lane * 8;
            #pragma unroll
            for (int t = 0; t < 8; ++t) {
                const short8 wf = *(const short8*)(woc + t * 512);
                a0[t] = __builtin_amdgcn_mfma_f32_16x16x32_bf16(wf, af0, a0[t], 0, 0, 0);
                a1[t] = __builtin_amdgcn_mfma_f32_16x16x32_bf16(wf, af1, a1[t], 0, 0, 0);
            }
        }
        #pragma unroll
        for (int t = 0; t < 8; ++t) {
            const int col = t * 16 + h4 * 4;
            const f32x4 bb = *(const f32x4*)(out_b + col);
            const f32x4 fv0 = *(const f32x4*)(feats + (size_t)ip0 * C + col);
            const f32x4 fv1 = *(const f32x4*)(feats + (size_t)ip1 * C + col);
            const f32x4 v0 = a0[t] + bb + fv0;
            const f32x4 v1 = a1[t] + bb + fv1;
            if (ig0 < n) *(f32x4*)(out + (size_t)ig0 * C + col) = v0;
            if (ig1 < n) *(f32x4*)(out + (size_t)ig1 * C + col) = v1;
        }
    }
}

// ---------------------------------------------------------------------------
extern "C" void kernel_launch(void* const* d_in, const int* in_sizes, int n_in,
                              void* d_out, int out_size, void* d_ws, size_t ws_size,
                              hipStream_t stream)
{
    const float* feats     = (const float*)d_in[0];
    const float* points    = (const float*)d_in[1];
    const int*   neighbors = (const int*)d_in[2];
    const float* ln_g      = (const float*)d_in[3];
    const float* ln_b      = (const float*)d_in[4];
    const float* cp_w1     = (const float*)d_in[5];
    const float* cp_b1     = (const float*)d_in[6];
    const float* cp_w2     = (const float*)d_in[7];
    const float* cp_b2     = (const float*)d_in[8];
    const float* bd_w1     = (const float*)d_in[9];
    const float* bd_b1     = (const float*)d_in[10];
    const float* bd_w2     = (const float*)d_in[11];
    const float* bd_b2     = (const float*)d_in[12];
    const float* mix_w1    = (const float*)d_in[13];
    const float* mix_b1    = (const float*)d_in[14];
    const float* mix_w2    = (const float*)d_in[15];
    const float* mix_b2    = (const float*)d_in[16];
    const float* gate_w1   = (const float*)d_in[17];
    const float* gate_b1   = (const float*)d_in[18];
    const float* gate_w2   = (const float*)d_in[19];
    const float* gate_b2   = (const float*)d_in[20];
    const float* out_w     = (const float*)d_in[21];
    const float* out_b     = (const float*)d_in[22];
    float* out = (float*)d_out;
    (void)n_in; (void)out_size; (void)ws_size;

    const int n = in_sizes[0] / C;

    // ws layout: xb u32[(n+1)*64] | xg u16[(n+1)*64] | pts4 f32[(n+1)*4]
    //            | wt bf16[WT_TOTAL] | partial f32[NB2*9] | stats f32[8]
    //            | mf u32[n*64] | bd f32[n]
    char* base = (char*)d_ws;
    unsigned* xb        = (unsigned*)base;
    unsigned short* xg  = (unsigned short*)(base + (size_t)(n + 1) * 256);
    float* pts4         = (float*)(base + (size_t)(n + 1) * 384);
    short* wt           = (short*)((char*)pts4 + (size_t)(n + 1) * 16);
    float* partial      = (float*)((char*)wt + (size_t)WT_TOTAL * 2);
    float* stats        = partial + NB2 * 9;
    unsigned* mf_g      = (unsigned*)((char*)stats + 32);
    float* bd_g         = (float*)((char*)mf_g + (size_t)n * 256);

    const int np4 = (n + 256) / 256;
    const int nln = (n + 3) / 4;
    const int nb_main = (n + PB - 1) / PB;

    prep_all<<<37 + np4 + NB2 + nln, 256, 0, stream>>>(
        mix_w1, gate_w1, cp_w2, mix_w2, gate_w2, out_w,
        points, feats, ln_g, ln_b,
        wt, xb, xg, pts4, partial, n, np4);
    pstat_final<<<1, 256, 0, stream>>>(partial, stats, n);
    gather_kernel<<<nb_main, 256, 0, stream>>>(
        xb, (const unsigned*)xg, pts4, neighbors,
        bd_w1, bd_b1, bd_w2, bd_b2, mf_g, bd_g, n);
    gemm_kernel<<<nb_main, 256, 0, stream>>>(
        xb, mf_g, bd_g, pts4, feats, stats, wt,
        cp_w1, cp_b1, cp_b2, mix_w1, mix_b1, mix_b2,
        gate_w1, gate_b1, gate_b2, out_b, out, n);
}

// Round 2
// 309.160 us; speedup vs baseline: 1.2977x; 1.2977x over previous
//
#include <hip/hip_runtime.h>
#include <math.h>

// Problem constants
constexpr int C    = 128;
constexpr int K    = 16;
constexpr int H    = 128;
constexpr int NB2  = 256;   // blocks for point-stat partial reduction
constexpr int WPTS = 32;    // points per wave
constexpr int PB   = 128;   // points per block (4 waves)
constexpr int HSU  = 68;    // activation row stride in u32 (136 bf16)

// Packed-weight offsets (bf16 elems) in ws: fragment order
constexpr int WT_MIX   = 0;        // K=384 -> 12 chunks
constexpr int WT_GATE  = 49152;    // K=256 -> 8 chunks
constexpr int WT_CP2   = 81920;    // K=128 -> 4 chunks
constexpr int WT_MIX2  = 98304;
constexpr int WT_GATE2 = 114688;
constexpr int WT_OUT   = 131072;
constexpr int WT_TOTAL = 147456;

typedef __attribute__((ext_vector_type(8))) short short8;
typedef __attribute__((ext_vector_type(4))) float f32x4;
typedef _Float16 h2 __attribute__((ext_vector_type(2)));

__device__ __forceinline__ short f2bf(float f) {
    unsigned u = __float_as_uint(f);
    unsigned r = (u + 0x7fffu + ((u >> 16) & 1u)) >> 16;
    return (short)r;
}
// packed f32x2 -> bf16x2 (RNE), single instruction
__device__ __forceinline__ unsigned cvt_pk_bf16(float lo, float hi) {
    unsigned r;
    asm("v_cvt_pk_bf16_f32 %0, %1, %2" : "=v"(r) : "v"(lo), "v"(hi));
    return r;
}
__device__ __forceinline__ float bflo(unsigned v) { return __uint_as_float(v << 16); }
__device__ __forceinline__ float bfhi(unsigned v) { return __uint_as_float(v & 0xffff0000u); }
__device__ __forceinline__ float rcpf(float v) { return __builtin_amdgcn_rcpf(v); }

// e5m2 = truncated fp16
__device__ __forceinline__ unsigned f2e5m2(float x) {
    union { _Float16 h; unsigned short u; } cv;
    cv.h = (_Float16)x;
    return ((unsigned)cv.u + 0x7Fu + ((cv.u >> 8) & 1u)) >> 8;
}

// A&S 7.1.26 erf-based exact-GELU (|erf err| < 1.5e-7)
__device__ __forceinline__ float gelu_f(float x) {
    float a = fabsf(x) * 0.70710678118654752440f;
    float t = rcpf(1.0f + 0.3275911f * a);
    float p = t * (0.254829592f + t * (-0.284496736f + t * (1.421413741f
            + t * (-1.453152027f + t * 1.061405429f))));
    float e = __expf(-a * a);
    float er = 1.0f - p * e;
    return 0.5f * x * (1.0f + copysignf(er, x));
}
__device__ __forceinline__ float sigm(float v) { return rcpf(1.0f + __expf(-v)); }

// ---------------------------------------------------------------------------
// Merged prep: weight pack | zero rows | pts4 | pstat partial | layernorm
// ---------------------------------------------------------------------------
__global__ __launch_bounds__(256) void prep_all(
    const float* __restrict__ mix_w1, const float* __restrict__ gate_w1,
    const float* __restrict__ cp_w2,  const float* __restrict__ mix_w2,
    const float* __restrict__ gate_w2, const float* __restrict__ out_w,
    const float* __restrict__ points, const float* __restrict__ feats,
    const float* __restrict__ ln_g, const float* __restrict__ ln_b,
    short* __restrict__ wt, unsigned* __restrict__ xb,
    unsigned short* __restrict__ xg, float* __restrict__ pts4,
    float* __restrict__ partial, int n, int np4)
{
    __shared__ float sm[256];
    const int b   = blockIdx.x;
    const int tid = threadIdx.x;

    if (b < 36) {
        const float* src; int off; int c; bool skip256 = false;
        if (b < 12)      { src = mix_w1;  off = WT_MIX;   c = b;      skip256 = true; }
        else if (b < 20) { src = gate_w1; off = WT_GATE;  c = b - 12; }
        else if (b < 24) { src = cp_w2;   off = WT_CP2;   c = b - 20; }
        else if (b < 28) { src = mix_w2;  off = WT_MIX2;  c = b - 24; }
        else if (b < 32) { src = gate_w2; off = WT_GATE2; c = b - 28; }
        else             { src = out_w;   off = WT_OUT;   c = b - 32; }
        for (int ii = 0; ii < 16; ++ii) {
            int e = ii * 256 + tid;
            int j = e & 7, l = (e >> 3) & 63, t = e >> 9;
            int k = c * 32 + ((l >> 4) * 8) + j;
            int nn = t * 16 + (l & 15);
            int kk = (skip256 && k >= 256) ? k + 1 : k;
            wt[off + c * 4096 + e] = f2bf(src[kk * C + nn]);
        }
        return;
    }
    if (b == 36) {
        if (tid < 64) xb[(size_t)n * 64 + tid] = 0u;
        else if (tid < 96) ((unsigned*)xg)[(size_t)n * 32 + (tid - 64)] = 0u;
        return;
    }
    if (b < 37 + np4) {
        int i = (b - 37) * 256 + tid;
        if (i < n) {
            pts4[i * 4 + 0] = points[i * 3 + 0];
            pts4[i * 4 + 1] = points[i * 3 + 1];
            pts4[i * 4 + 2] = points[i * 3 + 2];
            pts4[i * 4 + 3] = 0.0f;
        } else if (i == n) {
            pts4[i * 4 + 0] = 0.0f; pts4[i * 4 + 1] = 0.0f;
            pts4[i * 4 + 2] = 0.0f; pts4[i * 4 + 3] = 0.0f;
        }
        return;
    }
    if (b < 37 + np4 + NB2) {
        const int bb = b - 37 - np4;
        float s[3] = {0, 0, 0};
        float mn[3] = {1e30f, 1e30f, 1e30f};
        float mx[3] = {-1e30f, -1e30f, -1e30f};
        for (int i = bb * 256 + tid; i < n; i += NB2 * 256) {
            #pragma unroll
            for (int c = 0; c < 3; ++c) {
                float v = points[i * 3 + c];
                s[c] += v; mn[c] = fminf(mn[c], v); mx[c] = fmaxf(mx[c], v);
            }
        }
        for (int q = 0; q < 9; ++q) {
            float v = (q < 3) ? s[q] : (q < 6) ? mn[q - 3] : mx[q - 6];
            sm[tid] = v;
            __syncthreads();
            for (int o = 128; o > 0; o >>= 1) {
                if (tid < o) {
                    float a = sm[tid], c = sm[tid + o];
                    sm[tid] = (q < 3) ? a + c : (q < 6) ? fminf(a, c) : fmaxf(a, c);
                }
                __syncthreads();
            }
            if (tid == 0) partial[bb * 9 + q] = sm[0];
            __syncthreads();
        }
        return;
    }

    // layernorm role: one wave per point
    const int lane = tid & 63;
    const int wave = tid >> 6;
    const int i = (b - 37 - np4 - NB2) * 4 + wave;
    if (i >= n) return;
    const float2 f = *(const float2*)(feats + i * C + 2 * lane);
    float s = f.x + f.y;
    #pragma unroll
    for (int o = 32; o > 0; o >>= 1) s += __shfl_xor(s, o, 64);
    const float mu = s * (1.0f / C);
    const float d0 = f.x - mu, d1 = f.y - mu;
    float v = d0 * d0 + d1 * d1;
    #pragma unroll
    for (int o = 32; o > 0; o >>= 1) v += __shfl_xor(v, o, 64);
    const float rs = rsqrtf(v * (1.0f / C) + 1e-5f);
    const float x0 = d0 * rs * ln_g[2 * lane] + ln_b[2 * lane];
    const float x1 = d1 * rs * ln_g[2 * lane + 1] + ln_b[2 * lane + 1];
    xb[(size_t)i * 64 + lane] =
        (unsigned)(unsigned short)f2bf(x0) | ((unsigned)(unsigned short)f2bf(x1) << 16);
    xg[(size_t)i * 64 + lane] =
        (unsigned short)(f2e5m2(x0) | (f2e5m2(x1) << 8));
}

// ---------------------------------------------------------------------------
// Fully fused main kernel: 4 independent waves/block, 32 points each.
// No __syncthreads — all buffers wave-private row ranges. Gate-first GEMM
// ordering; per-wave pstat finalization; depth-2 gather prefetch.
// ---------------------------------------------------------------------------
__global__ __launch_bounds__(256, 2) void main_kernel(
    const unsigned* __restrict__ xb, const unsigned* __restrict__ xg,
    const float* __restrict__ pts4, const float* __restrict__ feats,
    const int* __restrict__ neighbors,
    const float* __restrict__ partial, const short* __restrict__ wt,
    const float* __restrict__ cp_w1, const float* __restrict__ cp_b1,
    const float* __restrict__ cp_b2,
    const float* __restrict__ bd_w1, const float* __restrict__ bd_b1,
    const float* __restrict__ bd_w2, const float* __restrict__ bd_b2,
    const float* __restrict__ mix_w1, const float* __restrict__ mix_b1,
    const float* __restrict__ mix_b2,
    const float* __restrict__ gate_w1, const float* __restrict__ gate_b1,
    const float* __restrict__ gate_b2,
    const float* __restrict__ out_b,
    float* __restrict__ out, int n)
{
    // LDS: mf[128][68]u32 | hid[128][68]u32 | denom[128] | cd[128] | bd[128]
    __shared__ __align__(16) char lds[71168];
    unsigned* mf_s  = (unsigned*)lds;
    unsigned* hid_s = (unsigned*)(lds + 34816);
    float* denom_s  = (float*)(lds + 69632);
    float* cd_s     = denom_s + 128;
    float* bd_s     = cd_s + 128;

    const int tid  = threadIdx.x;
    const int lane = tid & 63;
    const int w    = tid >> 6;
    const int m16  = lane & 15;
    const int h4   = lane >> 4;
    const int i0   = blockIdx.x * PB;
    const int wv32 = w * WPTS;
    const int i0w  = i0 + wv32;
    // per-wave neighbor scratch aliased into this wave's OWN hid rows
    int* nb_w = (int*)(hid_s + (size_t)wv32 * HSU);

    // ================= Phase A: neighbor metadata =================
    {
        const int p0 = lane >> 2;               // 0..15
        const int jb = 4 * (lane & 3);
        const int r0 = min(i0w + p0, n - 1);
        const int r1 = min(i0w + 16 + p0, n - 1);
        const int4 A0 = *(const int4*)(neighbors + (size_t)r0 * K + jb);
        const int4 A1 = *(const int4*)(neighbors + (size_t)r1 * K + jb);

        const int q00 = ((unsigned)A0.x < (unsigned)n) ? A0.x : n;
        const int q01 = ((unsigned)A0.y < (unsigned)n) ? A0.y : n;
        const int q02 = ((unsigned)A0.z < (unsigned)n) ? A0.z : n;
        const int q03 = ((unsigned)A0.w < (unsigned)n) ? A0.w : n;
        const int q10 = ((unsigned)A1.x < (unsigned)n) ? A1.x : n;
        const int q11 = ((unsigned)A1.y < (unsigned)n) ? A1.y : n;
        const int q12 = ((unsigned)A1.z < (unsigned)n) ? A1.z : n;
        const int q13 = ((unsigned)A1.w < (unsigned)n) ? A1.w : n;

        *(int4*)&nb_w[4 * lane]       = make_int4(q00, q01, q02, q03);
        *(int4*)&nb_w[256 + 4 * lane] = make_int4(q10, q11, q12, q13);

        float c0 = (float)((q00 != n) + (q01 != n) + (q02 != n) + (q03 != n));
        float c1 = (float)((q10 != n) + (q11 != n) + (q12 != n) + (q13 != n));
        c0 += __shfl_xor(c0, 1, 64); c0 += __shfl_xor(c0, 2, 64);
        c1 += __shfl_xor(c1, 1, 64); c1 += __shfl_xor(c1, 2, 64);
        const float d0 = fmaxf(c0, 1.0f), d1 = fmaxf(c1, 1.0f);
        if ((lane & 3) == 0) {
            denom_s[wv32 + p0]      = d0;
            denom_s[wv32 + 16 + p0] = d1;
        }

        f32x4 s0 = *(const f32x4*)(pts4 + 4 * q00);
        s0 += *(const f32x4*)(pts4 + 4 * q01);
        s0 += *(const f32x4*)(pts4 + 4 * q02);
        s0 += *(const f32x4*)(pts4 + 4 * q03);
        f32x4 s1 = *(const f32x4*)(pts4 + 4 * q10);
        s1 += *(const f32x4*)(pts4 + 4 * q11);
        s1 += *(const f32x4*)(pts4 + 4 * q12);
        s1 += *(const f32x4*)(pts4 + 4 * q13);
        #pragma unroll
        for (int c = 0; c < 3; ++c) {
            s0[c] += __shfl_xor(s0[c], 1, 64); s0[c] += __shfl_xor(s0[c], 2, 64);
            s1[c] += __shfl_xor(s1[c], 1, 64); s1[c] += __shfl_xor(s1[c], 2, 64);
        }
        if ((lane & 3) == 0) {
            const float rd0 = rcpf(d0), rd1 = rcpf(d1);
            const f32x4 pv0 = *(const f32x4*)(pts4 + 4 * r0);
            const f32x4 pv1 = *(const f32x4*)(pts4 + 4 * r1);
            const float e00 = pv0[0] - s0[0] * rd0, e01 = pv0[1] - s0[1] * rd0, e02 = pv0[2] - s0[2] * rd0;
            const float e10 = pv1[0] - s1[0] * rd1, e11 = pv1[1] - s1[1] * rd1, e12 = pv1[2] - s1[2] * rd1;
            cd_s[wv32 + p0]      = sqrtf(e00 * e00 + e01 * e01 + e02 * e02);
            cd_s[wv32 + 16 + p0] = sqrtf(e10 * e10 + e11 * e11 + e12 * e12);
        }
    }

    // ============ Per-wave point-stat finalization (replaces pstat_final) ====
    float mean0, mean1, mean2, rsc0, rsc1, rsc2;
    {
        float sx = 0, sy = 0, sz = 0;
        float mnx = 1e30f, mny = 1e30f, mnz = 1e30f;
        float mxx = -1e30f, mxy = -1e30f, mxz = -1e30f;
        #pragma unroll
        for (int t = 0; t < 4; ++t) {
            const float* pp = partial + (size_t)(lane + 64 * t) * 9;
            sx += pp[0]; sy += pp[1]; sz += pp[2];
            mnx = fminf(mnx, pp[3]); mny = fminf(mny, pp[4]); mnz = fminf(mnz, pp[5]);
            mxx = fmaxf(mxx, pp[6]); mxy = fmaxf(mxy, pp[7]); mxz = fmaxf(mxz, pp[8]);
        }
        #pragma unroll
        for (int o = 32; o > 0; o >>= 1) {
            sx += __shfl_xor(sx, o, 64); sy += __shfl_xor(sy, o, 64); sz += __shfl_xor(sz, o, 64);
            mnx = fminf(mnx, __shfl_xor(mnx, o, 64));
            mny = fminf(mny, __shfl_xor(mny, o, 64));
            mnz = fminf(mnz, __shfl_xor(mnz, o, 64));
            mxx = fmaxf(mxx, __shfl_xor(mxx, o, 64));
            mxy = fmaxf(mxy, __shfl_xor(mxy, o, 64));
            mxz = fmaxf(mxz, __shfl_xor(mxz, o, 64));
        }
        const float fn = (float)n;
        mean0 = sx / fn; mean1 = sy / fn; mean2 = sz / fn;
        rsc0 = rcpf(fmaxf(fmaxf(mxx - mean0, mean0 - mnx), 1e-6f));
        rsc1 = rcpf(fmaxf(fmaxf(mxy - mean1, mean1 - mny), 1e-6f));
        rsc2 = rcpf(fmaxf(fmaxf(mxz - mean2, mean2 - mnz), 1e-6f));
    }

    // ============ Phase B: depth-2 pipelined fp8 gather, 2 points/iter =======
    {
        const int ul   = lane & 31;
        const int half = lane >> 5;
        float w1f[4], w1c[4], b1v[4], w2v[4];
        #pragma unroll
        for (int j = 0; j < 4; ++j) {
            int u = ul + 32 * j;
            w1f[j] = bd_w1[u]; w1c[j] = bd_w1[H + u];
            b1v[j] = bd_b1[u]; w2v[j] = bd_w2[u];
        }
        const float bb2 = bd_b2[0];

        unsigned B0[16], B1[16], B2[16], B3[16];

        auto bstep = [&](unsigned (&cur)[16], unsigned (&pf)[16], int pr, bool do_pf) {
            if (do_pf) {
                #pragma unroll
                for (int k = 0; k < K; ++k)
                    pf[k] = xg[(size_t)nb_w[((pr + 2) * 2 + half) * K + k] * 32 + ul];
            }
            union UH { unsigned u; h2 h; };
            UH a02, a13; a02.u = 0u; a13.u = 0u;
            #pragma unroll
            for (int k = 0; k < K; ++k) {
                const unsigned u = cur[k];
                UH lo, hi;
                lo.u = (u << 8) & 0xFF00FF00u;
                hi.u = u & 0xFF00FF00u;
                a02.h += lo.h;
                a13.h += hi.h;
            }
            float f0 = (float)a02.h[0], f2 = (float)a02.h[1];
            float f1 = (float)a13.h[0], f3 = (float)a13.h[1];

            const int p = 2 * pr + half;
            const float rden = rcpf(denom_s[wv32 + p]);
            f0 *= rden; f1 *= rden; f2 *= rden; f3 *= rden;
            uint2 pk;
            pk.x = cvt_pk_bf16(f0, f1);
            pk.y = cvt_pk_bf16(f2, f3);
            *(uint2*)(mf_s + (size_t)(wv32 + p) * HSU + 2 * ul) = pk;

            const int ipp = min(i0w + p, n - 1);
            const uint2 xv = *(const uint2*)(xb + (size_t)ipp * 64 + 2 * ul);
            const float d0 = bflo(xv.x) - f0, d1 = bfhi(xv.x) - f1;
            const float d2 = bflo(xv.y) - f2, d3 = bfhi(xv.y) - f3;
            float ss = d0 * d0 + d1 * d1 + d2 * d2 + d3 * d3;
            #pragma unroll
            for (int o = 16; o > 0; o >>= 1) ss += __shfl_xor(ss, o, 64);
            const float fd = sqrtf(ss);
            const float cd = cd_s[wv32 + p];
            float s = 0.0f;
            #pragma unroll
            for (int j = 0; j < 4; ++j)
                s += gelu_f(fd * w1f[j] + cd * w1c[j] + b1v[j]) * w2v[j];
            #pragma unroll
            for (int o = 16; o > 0; o >>= 1) s += __shfl_xor(s, o, 64);
            if (ul == 0) bd_s[wv32 + p] = sigm(s + bb2);
        };

        // prologue: prefetch pr=0,1
        #pragma unroll
        for (int k = 0; k < K; ++k)
            B0[k] = xg[(size_t)nb_w[(0 + half) * K + k] * 32 + ul];
        #pragma unroll
        for (int k = 0; k < K; ++k)
            B1[k] = xg[(size_t)nb_w[(2 + half) * K + k] * 32 + ul];

        for (int g = 0; g < 3; ++g) {
            const int pr = 4 * g;
            bstep(B0, B2, pr + 0, true);
            bstep(B1, B3, pr + 1, true);
            bstep(B2, B0, pr + 2, true);
            bstep(B3, B1, pr + 3, true);
        }
        bstep(B0, B2, 12, true);
        bstep(B1, B3, 13, true);
        bstep(B2, B0, 14, false);
        bstep(B3, B1, 15, false);
    }

    // ================= GEMM phases (gate-first; 2 groups of 16 pts/wave) =====
    const int pr0 = wv32 + m16, pr1 = wv32 + 16 + m16;
    const int ig0 = i0 + pr0,   ig1 = i0 + pr1;
    const int ip0 = min(ig0, n - 1), ip1 = min(ig1, n - 1);
    const unsigned* xr0  = xb + (size_t)ip0 * 64;
    const unsigned* xr1  = xb + (size_t)ip1 * 64;
    const unsigned* mfr0 = mf_s + pr0 * HSU;
    const unsigned* mfr1 = mf_s + pr1 * HSU;
    unsigned* hr0 = hid_s + pr0 * HSU;
    unsigned* hr1 = hid_s + pr1 * HSU;

    const float bdp0 = bd_s[pr0], bdp1 = bd_s[pr1];

    // ---- gate1 (K=256: x | mf) + rank-1 + bias, GELU -> hid ----
    {
        f32x4 a0[8], a1[8];
        #pragma unroll
        for (int t = 0; t < 8; ++t) { a0[t] = (f32x4)0.0f; a1[t] = (f32x4)0.0f; }
        __builtin_amdgcn_s_setprio(1);
        #pragma unroll
        for (int c = 0; c < 8; ++c) {
            short8 af0, af1;
            if (c < 4) {
                af0 = *(const short8*)(xr0 + c * 16 + h4 * 4);
                af1 = *(const short8*)(xr1 + c * 16 + h4 * 4);
            } else {
                af0 = *(const short8*)(mfr0 + (c - 4) * 16 + h4 * 4);
                af1 = *(const short8*)(mfr1 + (c - 4) * 16 + h4 * 4);
            }
            const short* wgc = wt + WT_GATE + c * 4096 + lane * 8;
            #pragma unroll
            for (int t = 0; t < 8; ++t) {
                const short8 wf = *(const short8*)(wgc + t * 512);
                a0[t] = __builtin_amdgcn_mfma_f32_16x16x32_bf16(wf, af0, a0[t], 0, 0, 0);
                a1[t] = __builtin_amdgcn_mfma_f32_16x16x32_bf16(wf, af1, a1[t], 0, 0, 0);
            }
        }
        __builtin_amdgcn_s_setprio(0);
        #pragma unroll
        for (int t = 0; t < 8; ++t) {
            const int col = t * 16 + h4 * 4;
            const f32x4 wb = *(const f32x4*)(gate_w1 + 256 * C + col);
            const f32x4 bb = *(const f32x4*)(gate_b1 + col);
            const f32x4 v0 = a0[t] + bdp0 * wb + bb;
            const f32x4 v1 = a1[t] + bdp1 * wb + bb;
            uint2 pk0, pk1;
            pk0.x = cvt_pk_bf16(gelu_f(v0[0]), gelu_f(v0[1]));
            pk0.y = cvt_pk_bf16(gelu_f(v0[2]), gelu_f(v0[3]));
            pk1.x = cvt_pk_bf16(gelu_f(v1[0]), gelu_f(v1[1]));
            pk1.y = cvt_pk_bf16(gelu_f(v1[2]), gelu_f(v1[3]));
            *(uint2*)(hr0 + 8 * t + 2 * h4) = pk0;
            *(uint2*)(hr1 + 8 * t + 2 * h4) = pk1;
        }
    }

    // ---- gate2 -> sigmoid packed bf16 in regs (16 u32 live downstream) ----
    uint2 gpk0[8], gpk1[8];
    {
        f32x4 a0[8], a1[8];
        #pragma unroll
        for (int t = 0; t < 8; ++t) { a0[t] = (f32x4)0.0f; a1[t] = (f32x4)0.0f; }
        __builtin_amdgcn_s_setprio(1);
        #pragma unroll
        for (int c = 0; c < 4; ++c) {
            const short8 af0 = *(const short8*)(hr0 + c * 16 + h4 * 4);
            const short8 af1 = *(const short8*)(hr1 + c * 16 + h4 * 4);
            const short* wgc = wt + WT_GATE2 + c * 4096 + lane * 8;
            #pragma unroll
            for (int t = 0; t < 8; ++t) {
                const short8 wf = *(const short8*)(wgc + t * 512);
                a0[t] = __builtin_amdgcn_mfma_f32_16x16x32_bf16(wf, af0, a0[t], 0, 0, 0);
                a1[t] = __builtin_amdgcn_mfma_f32_16x16x32_bf16(wf, af1, a1[t], 0, 0, 0);
            }
        }
        __builtin_amdgcn_s_setprio(0);
        #pragma unroll
        for (int t = 0; t < 8; ++t) {
            const f32x4 bb = *(const f32x4*)(gate_b2 + t * 16 + h4 * 4);
            gpk0[t].x = cvt_pk_bf16(sigm(a0[t][0] + bb[0]), sigm(a0[t][1] + bb[1]));
            gpk0[t].y = cvt_pk_bf16(sigm(a0[t][2] + bb[2]), sigm(a0[t][3] + bb[3]));
            gpk1[t].x = cvt_pk_bf16(sigm(a1[t][0] + bb[0]), sigm(a1[t][1] + bb[1]));
            gpk1[t].y = cvt_pk_bf16(sigm(a1[t][2] + bb[2]), sigm(a1[t][3] + bb[3]));
        }
    }

    // ---- cp MLP: hidden from regs, cp2 GEMM -> ce into hid ----
    {
        const f32x4 pv0 = *(const f32x4*)(pts4 + 4 * ip0);
        const f32x4 pv1 = *(const f32x4*)(pts4 + 4 * ip1);
        const float px0 = (pv0[0] - mean0) * rsc0;
        const float py0 = (pv0[1] - mean1) * rsc1;
        const float pz0 = (pv0[2] - mean2) * rsc2;
        const float px1 = (pv1[0] - mean0) * rsc0;
        const float py1 = (pv1[1] - mean1) * rsc1;
        const float pz1 = (pv1[2] - mean2) * rsc2;
        f32x4 a0[8], a1[8];
        #pragma unroll
        for (int t = 0; t < 8; ++t) { a0[t] = (f32x4)0.0f; a1[t] = (f32x4)0.0f; }
        #pragma unroll
        for (int c = 0; c < 4; ++c) {
            union { unsigned u[4]; short8 s; } cu0, cu1;
            #pragma unroll
            for (int jj = 0; jj < 4; ++jj) {
                const int hh = c * 32 + h4 * 8 + 2 * jj;
                const float wa0 = cp_w1[hh],     wb0 = cp_w1[H + hh],     wc0 = cp_w1[2 * H + hh];
                const float wa1 = cp_w1[hh + 1], wb1 = cp_w1[H + hh + 1], wc1 = cp_w1[2 * H + hh + 1];
                const float bb0 = cp_b1[hh], bb1 = cp_b1[hh + 1];
                cu0.u[jj] = cvt_pk_bf16(gelu_f(bb0 + px0 * wa0 + py0 * wb0 + pz0 * wc0),
                                        gelu_f(bb1 + px0 * wa1 + py0 * wb1 + pz0 * wc1));
                cu1.u[jj] = cvt_pk_bf16(gelu_f(bb0 + px1 * wa0 + py1 * wb0 + pz1 * wc0),
                                        gelu_f(bb1 + px1 * wa1 + py1 * wb1 + pz1 * wc1));
            }
            const short* wcp = wt + WT_CP2 + c * 4096 + lane * 8;
            __builtin_amdgcn_s_setprio(1);
            #pragma unroll
            for (int t = 0; t < 8; ++t) {
                const short8 wf = *(const short8*)(wcp + t * 512);
                a0[t] = __builtin_amdgcn_mfma_f32_16x16x32_bf16(wf, cu0.s, a0[t], 0, 0, 0);
                a1[t] = __builtin_amdgcn_mfma_f32_16x16x32_bf16(wf, cu1.s, a1[t], 0, 0, 0);
            }
            __builtin_amdgcn_s_setprio(0);
        }
        #pragma unroll
        for (int t = 0; t < 8; ++t) {
            const f32x4 bb = *(const f32x4*)(cp_b2 + t * 16 + h4 * 4);
            const f32x4 v0 = a0[t] + bb, v1 = a1[t] + bb;
            uint2 pk0, pk1;
            pk0.x = cvt_pk_bf16(v0[0], v0[1]); pk0.y = cvt_pk_bf16(v0[2], v0[3]);
            pk1.x = cvt_pk_bf16(v1[0], v1[1]); pk1.y = cvt_pk_bf16(v1[2], v1[3]);
            *(uint2*)(hr0 + 8 * t + 2 * h4) = pk0;
            *(uint2*)(hr1 + 8 * t + 2 * h4) = pk1;
        }
    }

    // ---- mix1 (K=384: x | mf | ce) + rank-1 + bias, GELU -> hid ----
    {
        f32x4 a0[8], a1[8];
        #pragma unroll
        for (int t = 0; t < 8; ++t) { a0[t] = (f32x4)0.0f; a1[t] = (f32x4)0.0f; }
        __builtin_amdgcn_s_setprio(1);
        #pragma unroll
        for (int c = 0; c < 12; ++c) {
            short8 af0, af1;
            if (c < 4) {
                af0 = *(const short8*)(xr0 + c * 16 + h4 * 4);
                af1 = *(const short8*)(xr1 + c * 16 + h4 * 4);
            } else if (c < 8) {
                af0 = *(const short8*)(mfr0 + (c - 4) * 16 + h4 * 4);
                af1 = *(const short8*)(mfr1 + (c - 4) * 16 + h4 * 4);
            } else {
                af0 = *(const short8*)(hr0 + (c - 8) * 16 + h4 * 4);
                af1 = *(const short8*)(hr1 + (c - 8) * 16 + h4 * 4);
            }
            const short* wmc = wt + WT_MIX + c * 4096 + lane * 8;
            #pragma unroll
            for (int t = 0; t < 8; ++t) {
                const short8 wf = *(const short8*)(wmc + t * 512);
                a0[t] = __builtin_amdgcn_mfma_f32_16x16x32_bf16(wf, af0, a0[t], 0, 0, 0);
                a1[t] = __builtin_amdgcn_mfma_f32_16x16x32_bf16(wf, af1, a1[t], 0, 0, 0);
            }
        }
        __builtin_amdgcn_s_setprio(0);
        #pragma unroll
        for (int t = 0; t < 8; ++t) {
            const int col = t * 16 + h4 * 4;
            const f32x4 wb = *(const f32x4*)(mix_w1 + 256 * C + col);
            const f32x4 bb = *(const f32x4*)(mix_b1 + col);
            const f32x4 v0 = a0[t] + bdp0 * wb + bb;
            const f32x4 v1 = a1[t] + bdp1 * wb + bb;
            uint2 pk0, pk1;
            pk0.x = cvt_pk_bf16(gelu_f(v0[0]), gelu_f(v0[1]));
            pk0.y = cvt_pk_bf16(gelu_f(v0[2]), gelu_f(v0[3]));
            pk1.x = cvt_pk_bf16(gelu_f(v1[0]), gelu_f(v1[1]));
            pk1.y = cvt_pk_bf16(gelu_f(v1[2]), gelu_f(v1[3]));
            *(uint2*)(hr0 + 8 * t + 2 * h4) = pk0;
            *(uint2*)(hr1 + 8 * t + 2 * h4) = pk1;
        }
    }

    // ---- mix2 -> refined; gate-multiply -> hid (overwrite) ----
    {
        f32x4 a0[8], a1[8];
        #pragma unroll
        for (int t = 0; t < 8; ++t) { a0[t] = (f32x4)0.0f; a1[t] = (f32x4)0.0f; }
        __builtin_amdgcn_s_setprio(1);
        #pragma unroll
        for (int c = 0; c < 4; ++c) {
            const short8 af0 = *(const short8*)(hr0 + c * 16 + h4 * 4);
            const short8 af1 = *(const short8*)(hr1 + c * 16 + h4 * 4);
            const short* wmc = wt + WT_MIX2 + c * 4096 + lane * 8;
            #pragma unroll
            for (int t = 0; t < 8; ++t) {
                const short8 wf = *(const short8*)(wmc + t * 512);
                a0[t] = __builtin_amdgcn_mfma_f32_16x16x32_bf16(wf, af0, a0[t], 0, 0, 0);
                a1[t] = __builtin_amdgcn_mfma_f32_16x16x32_bf16(wf, af1, a1[t], 0, 0, 0);
            }
        }
        __builtin_amdgcn_s_setprio(0);
        #pragma unroll
        for (int t = 0; t < 8; ++t) {
            const f32x4 bb = *(const f32x4*)(mix_b2 + t * 16 + h4 * 4);
            const f32x4 v0 = a0[t] + bb, v1 = a1[t] + bb;
            uint2 pk0, pk1;
            pk0.x = cvt_pk_bf16(bflo(gpk0[t].x) * v0[0], bfhi(gpk0[t].x) * v0[1]);
            pk0.y = cvt_pk_bf16(bflo(gpk0[t].y) * v0[2], bfhi(gpk0[t].y) * v0[3]);
            pk1.x = cvt_pk_bf16(bflo(gpk1[t].x) * v1[0], bfhi(gpk1[t].x) * v1[1]);
            pk1.y = cvt_pk_bf16(bflo(gpk1[t].y) * v1[2], bfhi(gpk1[t].y) * v1[3]);
            *(uint2*)(hr0 + 8 * t + 2 * h4) = pk0;
            *(uint2*)(hr1 + 8 * t + 2 * h4) = pk1;
        }
    }

    // ---- out GEMM + bias + residual -> global store ----
    {
        f32x4 a0[8], a1[8];
        #pragma unroll
        for (int t = 0; t < 8; ++t) { a0[t] = (f32x4)0.0f; a1[t] = (f32x4)0.0f; }
        __builtin_amdgcn_s_setprio(1);
        #pragma unroll
        for (int c = 0; c < 4; ++c) {
            const short8 af0 = *(const short8*)(hr0 + c * 16 + h4 * 4);
            const short8 af1 = *(const short8*)(hr1 + c * 16 + h4 * 4);
            const short* woc = wt + WT_OUT + c * 4096 + lane * 8;
            #pragma unroll
            for (int t = 0; t < 8; ++t) {
                const short8 wf = *(const short8*)(woc + t * 512);
                a0[t] = __builtin_amdgcn_mfma_f32_16x16x32_bf16(wf, af0, a0[t], 0, 0, 0);
                a1[t] = __builtin_amdgcn_mfma_f32_16x16x32_bf16(wf, af1, a1[t], 0, 0, 0);
            }
        }
        __builtin_amdgcn_s_setprio(0);
        #pragma unroll
        for (int t = 0; t < 8; ++t) {
            const int col = t * 16 + h4 * 4;
            const f32x4 bb = *(const f32x4*)(out_b + col);
            const f32x4 fv0 = *(const f32x4*)(feats + (size_t)ip0 * C + col);
            const f32x4 fv1 = *(const f32x4*)(feats + (size_t)ip1 * C + col);
            const f32x4 v0 = a0[t] + bb + fv0;
            const f32x4 v1 = a1[t] + bb + fv1;
            if (ig0 < n) *(f32x4*)(out + (size_t)ig0 * C + col) = v0;
            if (ig1 < n) *(f32x4*)(out + (size_t)ig1 * C + col) = v1;
        }
    }
}

// ---------------------------------------------------------------------------
extern "C" void kernel_launch(void* const* d_in, const int* in_sizes, int n_in,
                              void* d_out, int out_size, void* d_ws, size_t ws_size,
                              hipStream_t stream)
{
    const float* feats     = (const float*)d_in[0];
    const float* points    = (const float*)d_in[1];
    const int*   neighbors = (const int*)d_in[2];
    const float* ln_g      = (const float*)d_in[3];
    const float* ln_b      = (const float*)d_in[4];
    const float* cp_w1     = (const float*)d_in[5];
    const float* cp_b1     = (const float*)d_in[6];
    const float* cp_w2     = (const float*)d_in[7];
    const float* cp_b2     = (const float*)d_in[8];
    const float* bd_w1     = (const float*)d_in[9];
    const float* bd_b1     = (const float*)d_in[10];
    const float* bd_w2     = (const float*)d_in[11];
    const float* bd_b2     = (const float*)d_in[12];
    const float* mix_w1    = (const float*)d_in[13];
    const float* mix_b1    = (const float*)d_in[14];
    const float* mix_w2    = (const float*)d_in[15];
    const float* mix_b2    = (const float*)d_in[16];
    const float* gate_w1   = (const float*)d_in[17];
    const float* gate_b1   = (const float*)d_in[18];
    const float* gate_w2   = (const float*)d_in[19];
    const float* gate_b2   = (const float*)d_in[20];
    const float* out_w     = (const float*)d_in[21];
    const float* out_b     = (const float*)d_in[22];
    float* out = (float*)d_out;
    (void)n_in; (void)out_size; (void)ws_size;

    const int n = in_sizes[0] / C;

    // ws layout: xb u32[(n+1)*64] | xg u16[(n+1)*64] | pts4 f32[(n+1)*4]
    //            | wt bf16[WT_TOTAL] | partial f32[NB2*9]
    char* base = (char*)d_ws;
    unsigned* xb        = (unsigned*)base;
    unsigned short* xg  = (unsigned short*)(base + (size_t)(n + 1) * 256);
    float* pts4         = (float*)(base + (size_t)(n + 1) * 384);
    short* wt           = (short*)((char*)pts4 + (size_t)(n + 1) * 16);
    float* partial      = (float*)((char*)wt + (size_t)WT_TOTAL * 2);

    const int np4 = (n + 256) / 256;
    const int nln = (n + 3) / 4;
    const int nb_main = (n + PB - 1) / PB;

    prep_all<<<37 + np4 + NB2 + nln, 256, 0, stream>>>(
        mix_w1, gate_w1, cp_w2, mix_w2, gate_w2, out_w,
        points, feats, ln_g, ln_b,
        wt, xb, xg, pts4, partial, n, np4);
    main_kernel<<<nb_main, 256, 0, stream>>>(
        xb, (const unsigned*)xg, pts4, feats, neighbors, partial, wt,
        cp_w1, cp_b1, cp_b2, bd_w1, bd_b1, bd_w2, bd_b2,
        mix_w1, mix_b1, mix_b2, gate_w1, gate_b1, gate_b2,
        out_b, out, n);
}